// Round 5
// baseline (370.627 us; speedup 1.0000x reference)
//
#include <hip/hip_runtime.h>
#include <stdint.h>

#pragma clang fp contract(off)

#define BB 16
#define NN 25200
#define ROW 85
#define NCLS 80
#define TK 2048
#define CAND 4096
#define NBIN 4096
#define MAXDET 1000
#define CONF 0.25f
#define IOUT 0.45f
#define MAXWH 4096.0f

typedef float fvec4 __attribute__((ext_vector_type(4)));

// ---------------- Stage 1: coalesced LDS-staged scores + argmax + histogram ----------------
// One wave per 64 consecutive rows. 64*85*4 B = 21760 B is 16B-aligned at every
// 64-row boundary, so the wave streams it with fully-coalesced dwordx4 loads
// (every 128B line fetched exactly once), then reduces per-row from LDS.
__global__ __launch_bounds__(64) void score_kernel(const float* __restrict__ pred,
                                                   float* __restrict__ scores,
                                                   unsigned char* __restrict__ cls,
                                                   unsigned int* __restrict__ hist) {
  int b = blockIdx.y;
  int r0 = blockIdx.x * 64;
  int nr = NN - r0; if (nr > 64) nr = 64;   // 48 in the last block
  int lane = threadIdx.x;
  __shared__ float lds[64 * ROW];           // 21760 B
  const float* base = pred + ((size_t)b * NN + r0) * ROW;  // 16B-aligned
  int tot = nr * ROW;                       // 5440 or 4080, both %4==0
  for (int i = lane * 4; i < tot; i += 256) {
    fvec4 v = *(const fvec4*)(base + i);    // aligned global dwordx4
    *(fvec4*)(&lds[i]) = v;                 // aligned ds_write_b128
  }
  __syncthreads();
  if (lane < nr) {
    const float* row = &lds[lane * ROW];    // stride 85 dwords: 2-way bank alias (free)
    float obj = row[4];
    float best = row[5];
    int bid = 0;
#pragma unroll
    for (int c = 1; c < NCLS; ++c) {
      float p = row[5 + c];
      if (p > best) { best = p; bid = c; }  // strict > keeps first max (argmax semantics)
    }
    float score = obj * best;
    bool valid = (obj > CONF) && (score > CONF);
    float sout = valid ? score : 0.0f;
    int n = r0 + lane;
    scores[(size_t)b * NN + n] = sout;
    cls[(size_t)b * NN + n] = (unsigned char)bid;
    if (valid) {
      unsigned int u = __float_as_uint(sout);   // in (0x3E800000, 0x3F800000]
      unsigned int bin = (u - 0x3E800001u) >> 12;
      if (bin > NBIN - 1) bin = NBIN - 1;
      atomicAdd(&hist[(size_t)b * NBIN + bin], 1u);
    }
  }
}

// ---------------- Stage 2a: pivot bin per batch (parallel suffix-scan) ----------------
__global__ __launch_bounds__(256) void pivot_kernel(const unsigned int* __restrict__ hist,
                                                    int* __restrict__ pivP) {
  int b = blockIdx.x;
  int t = threadIdx.x;
  const unsigned int* h = hist + (size_t)b * NBIN;
  __shared__ int sfx[256];
  int s = 0;
  for (int k = 0; k < 16; ++k) s += (int)h[t * 16 + k];
  sfx[t] = s;
  __syncthreads();
  for (int off = 1; off < 256; off <<= 1) {
    int v = (t + off < 256) ? sfx[t + off] : 0;
    __syncthreads();
    sfx[t] += v;
    __syncthreads();
  }
  // sfx[t] = sum of groups t..255 (suffix, decreasing in t)
  int above = (t == 255) ? 0 : sfx[t + 1];
  if (sfx[t] >= TK && above < TK) {         // exactly one t (if total >= TK)
    int cum = above;
    for (int bin = t * 16 + 15; bin >= t * 16; --bin) {
      cum += (int)h[bin];
      if (cum >= TK) { pivP[b] = bin; break; }
    }
  }
  if (t == 0 && sfx[0] < TK) pivP[b] = 0;   // never with this data; safety
}

// ---------------- Stage 2b: grid-wide gather of candidates (bin >= P) ----------------
__global__ __launch_bounds__(256) void gather_kernel(const float* __restrict__ scores,
                                                     const int* __restrict__ pivP,
                                                     unsigned long long* __restrict__ ckey,
                                                     int* __restrict__ cnt) {
  int n = blockIdx.x * blockDim.x + threadIdx.x;
  int b = blockIdx.y;
  if (n >= NN) return;
  unsigned int u = __float_as_uint(scores[(size_t)b * NN + n]);
  if (u > 0x3E800000u) {
    unsigned int bin = (u - 0x3E800001u) >> 12;
    if (bin > NBIN - 1) bin = NBIN - 1;
    if (bin >= (unsigned int)pivP[b]) {
      int slot = atomicAdd(&cnt[b], 1);
      if (slot < CAND)
        ckey[(size_t)b * CAND + slot] = ((unsigned long long)u << 32) | (unsigned int)(~n);
    }
  }
}

// ---------------- Stage 2c: rank-place (1 block per 256 slots) + epilogue ----------------
__global__ __launch_bounds__(256) void rank_kernel(const float* __restrict__ pred,
                                                   const unsigned char* __restrict__ cls,
                                                   const unsigned long long* __restrict__ ckey,
                                                   const int* __restrict__ cnt,
                                                   float* __restrict__ tops,
                                                   float* __restrict__ boxes,
                                                   int* __restrict__ clsk) {
  int b = blockIdx.y;
  int t = threadIdx.x;
  int slot = blockIdx.x * 256 + t;
  int C = cnt[b]; if (C > CAND) C = CAND;
  __shared__ unsigned long long lk[CAND];  // 32 KB; only first C used
  const unsigned long long* gk = ckey + (size_t)b * CAND;
  for (int i = t; i < C; i += 256) lk[i] = gk[i];
  __syncthreads();

  if (slot < C) {
    unsigned long long mk = lk[slot];
    int r = 0;
    int j = 0;
    unsigned long long pf[8];
    for (; j + 8 <= C; j += 8) {
#pragma unroll
      for (int k = 0; k < 8; ++k) pf[k] = lk[j + k];   // broadcast, conflict-free
#pragma unroll
      for (int k = 0; k < 8; ++k) r += (pf[k] > mk) ? 1 : 0;
    }
    for (; j < C; ++j) r += (lk[j] > mk) ? 1 : 0;

    if (r < TK) {  // rank IS the final top_k position (unique keys)
      unsigned int ub = (unsigned int)(mk >> 32);
      int idx = (int)(~(unsigned int)mk);
      tops[(size_t)b * TK + r] = __uint_as_float(ub);
      clsk[(size_t)b * TK + r] = (int)cls[(size_t)b * NN + idx];
      const float* rowp = pred + ((size_t)b * NN + idx) * ROW;
      float cx = rowp[0], cy = rowp[1], w = rowp[2], h = rowp[3];
      float hw = w * 0.5f, hh = h * 0.5f;
      float* ob = boxes + ((size_t)b * TK + r) * 4;
      ob[0] = cx - hw; ob[1] = cy - hh; ob[2] = cx + hw; ob[3] = cy + hh;
    }
  } else if (slot < TK) {
    // positions [C, TK) are never ranked into — zero-pad (only if C < 2048)
    tops[(size_t)b * TK + slot] = 0.0f;
    clsk[(size_t)b * TK + slot] = 0;
    float* ob = boxes + ((size_t)b * TK + slot) * 4;
    ob[0] = 0.f; ob[1] = 0.f; ob[2] = 0.f; ob[3] = 0.f;
  }
}

// ---------------- Stage 3: greedy NMS, one wave per (batch, class) ----------------
__global__ __launch_bounds__(64) void nms_kernel(const float* __restrict__ tops,
                                                 const float* __restrict__ boxes,
                                                 const int* __restrict__ clsk,
                                                 int* __restrict__ keep) {
  int c = blockIdx.x;
  int b = blockIdx.y;
  int lane = threadIdx.x;
  __shared__ float sx1[TK], sy1[TK], sx2[TK], sy2[TK];
  __shared__ unsigned short spos[TK];
  __shared__ unsigned char skp[TK];

  // prefetch all clsk/tops chunks into registers: independent loads, one latency
  int myc[32];
  float mytop[32];
#pragma unroll
  for (int it = 0; it < 32; ++it) {
    int j = it * 64 + lane;
    myc[it] = clsk[(size_t)b * TK + j];
    mytop[it] = tops[(size_t)b * TK + j];
  }

  float shift = (float)c * MAXWH;
  int m = 0;
#pragma unroll 4
  for (int it = 0; it < 32; ++it) {
    int j = it * 64 + lane;
    bool match = (myc[it] == c);
    unsigned long long bal = __ballot(match);
    int mp = m + __popcll(bal & ((1ull << lane) - 1ull));
    if (match) {
      spos[mp] = (unsigned short)j;
      const float* bx = boxes + ((size_t)b * TK + j) * 4;
      sx1[mp] = bx[0] + shift;
      sy1[mp] = bx[1] + shift;
      sx2[mp] = bx[2] + shift;
      sy2[mp] = bx[3] + shift;
      skp[mp] = (mytop[it] > 0.0f) ? 1 : 0;
    }
    m += (int)__popcll(bal);
  }
  __syncthreads();

  for (int i = 0; i < m; ++i) {
    __syncthreads();
    if (!skp[i]) continue;  // uniform across the wave
    float ax1 = sx1[i], ay1 = sy1[i], ax2 = sx2[i], ay2 = sy2[i];
    float aarea = (ax2 - ax1) * (ay2 - ay1);
    for (int j = i + 1 + lane; j < m; j += 64) {
      float bx1 = sx1[j], by1 = sy1[j], bx2 = sx2[j], by2 = sy2[j];
      float ltx = fmaxf(ax1, bx1), lty = fmaxf(ay1, by1);
      float rbx = fminf(ax2, bx2), rby = fminf(ay2, by2);
      float iw = fmaxf(rbx - ltx, 0.0f);
      float ih = fmaxf(rby - lty, 0.0f);
      float inter = iw * ih;
      float barea = (bx2 - bx1) * (by2 - by1);
      float iou = inter / (aarea + barea - inter + 1e-7f);
      if (iou > IOUT) skp[j] = 0;
    }
  }
  __syncthreads();

  for (int i = lane; i < m; i += 64) {
    keep[(size_t)b * TK + spos[i]] = skp[i];
  }
}

// ---------------- Stage 4: compact first 1000 kept + padding ----------------
__global__ __launch_bounds__(256) void out_kernel(const float* __restrict__ tops,
                                                  const float* __restrict__ boxes,
                                                  const int* __restrict__ clsk,
                                                  const int* __restrict__ keep,
                                                  float* __restrict__ out) {
  int b = blockIdx.x;
  int t = threadIdx.x;
  __shared__ int scnt[256];
  const int CH = TK / 256;  // 8
  int base = t * CH;
  int kp[CH];
  int cnt = 0;
  for (int k = 0; k < CH; ++k) {
    kp[k] = keep[(size_t)b * TK + base + k];
    cnt += kp[k];
  }
  scnt[t] = cnt;
  __syncthreads();
  for (int off = 1; off < 256; off <<= 1) {
    int v = (t >= off) ? scnt[t - off] : 0;
    __syncthreads();
    scnt[t] += v;
    __syncthreads();
  }
  int r = scnt[t] - cnt;
  int K = scnt[255];
  for (int k = 0; k < CH; ++k) {
    if (kp[k]) {
      if (r < MAXDET) {
        int j = base + k;
        float* o = out + ((size_t)b * MAXDET + r) * 6;
        const float* bx = boxes + ((size_t)b * TK + j) * 4;
        o[0] = bx[0]; o[1] = bx[1]; o[2] = bx[2]; o[3] = bx[3];
        o[4] = tops[(size_t)b * TK + j];
        o[5] = (float)clsk[(size_t)b * TK + j];
      }
      ++r;
    }
  }
  int Kc = K < MAXDET ? K : MAXDET;
  for (int r2 = Kc + t; r2 < MAXDET; r2 += 256) {
    float* o = out + ((size_t)b * MAXDET + r2) * 6;
    o[0] = 0.0f; o[1] = 0.0f; o[2] = 0.0f; o[3] = 0.0f; o[4] = 0.0f; o[5] = -1.0f;
  }
}

extern "C" void kernel_launch(void* const* d_in, const int* in_sizes, int n_in,
                              void* d_out, int out_size, void* d_ws, size_t ws_size,
                              hipStream_t stream) {
  const float* pred = (const float*)d_in[0];
  float* out = (float*)d_out;

  char* ws = (char*)d_ws;
  size_t off = 0;
  float* scores = (float*)(ws + off);         off += (size_t)BB * NN * 4;     // 1.6 MB
  unsigned char* cls = (unsigned char*)(ws + off); off += (size_t)BB * NN;    // 0.4 MB
  off = (off + 255) & ~(size_t)255;
  float* tops   = (float*)(ws + off);         off += (size_t)BB * TK * 4;
  float* boxes  = (float*)(ws + off);         off += (size_t)BB * TK * 16;
  int*   clsk   = (int*)(ws + off);           off += (size_t)BB * TK * 4;
  int*   keep   = (int*)(ws + off);           off += (size_t)BB * TK * 4;
  unsigned long long* ckey = (unsigned long long*)(ws + off); off += (size_t)BB * CAND * 8; // 0.5 MB
  unsigned int* hist = (unsigned int*)(ws + off); off += (size_t)BB * NBIN * 4;             // 256 KB
  int*   cnt    = (int*)(ws + off);           off += (size_t)BB * 4;
  int*   pivP   = (int*)(ws + off);           off += (size_t)BB * 4;
  (void)ws_size; (void)in_sizes; (void)n_in; (void)out_size;

  // zero hist + cnt (contiguous) in one memset
  hipMemsetAsync(hist, 0, (size_t)BB * NBIN * 4 + (size_t)BB * 4, stream);
  score_kernel<<<dim3((NN + 63) / 64, BB), 64, 0, stream>>>(pred, scores, cls, hist);
  pivot_kernel<<<BB, 256, 0, stream>>>(hist, pivP);
  gather_kernel<<<dim3((NN + 255) / 256, BB), 256, 0, stream>>>(scores, pivP, ckey, cnt);
  rank_kernel<<<dim3(CAND / 256, BB), 256, 0, stream>>>(pred, cls, ckey, cnt, tops, boxes, clsk);
  nms_kernel<<<dim3(NCLS, BB), 64, 0, stream>>>(tops, boxes, clsk, keep);
  out_kernel<<<BB, 256, 0, stream>>>(tops, boxes, clsk, keep, out);
}

// Round 6
// 349.782 us; speedup vs baseline: 1.0596x; 1.0596x over previous
//
#include <hip/hip_runtime.h>
#include <stdint.h>

#pragma clang fp contract(off)

#define BB 16
#define NN 25200
#define ROW 85
#define NCLS 80
#define TK 2048
#define CAND 4096
#define NBIN 4096
#define MAXDET 1000
#define CONF 0.25f
#define IOUT 0.45f
#define MAXWH 4096.0f

typedef float fvec4 __attribute__((ext_vector_type(4)));

// ---------------- Stage 1: coalesced LDS-staged scores + argmax + histogram ----------------
// 256 threads (4 waves) per 64 rows: all threads stage 64*85 floats with coalesced
// dwordx4 (every 128B line fetched once), then the 80-class argmax is split into
// 4 partials (wave p scans classes [20p,20p+20)) combined in ascending-part order
// with strict > — preserving exact first-max argmax semantics.
// LDS 23.8 KB -> 6 blocks/CU = 24 waves/CU.
__global__ __launch_bounds__(256) void score_kernel(const float* __restrict__ pred,
                                                    float* __restrict__ scores,
                                                    unsigned char* __restrict__ cls,
                                                    unsigned int* __restrict__ hist) {
  int b = blockIdx.y;
  int r0 = blockIdx.x * 64;
  int nr = NN - r0; if (nr > 64) nr = 64;   // 48 in the last block
  int tid = threadIdx.x;
  __shared__ float lds[64 * ROW];           // 21760 B
  __shared__ float pbest[4][64];
  __shared__ int   pbid[4][64];
  const float* base = pred + ((size_t)b * NN + r0) * ROW;  // 16B-aligned (64*85*4 = 1360*16)
  int tot = nr * ROW;                       // 5440 or 4080, both %4==0
  for (int i = tid * 4; i < tot; i += 1024) {
    fvec4 v = *(const fvec4*)(base + i);    // aligned global dwordx4
    *(fvec4*)(&lds[i]) = v;                 // aligned ds_write_b128
  }
  __syncthreads();

  int p = tid >> 6;       // part 0..3
  int r = tid & 63;       // row within block
  if (r < nr) {
    const float* row = &lds[r * ROW];       // stride 85: free 2-way bank alias
    int c0 = 20 * p;
    float best = row[5 + c0];
    int bid = c0;
#pragma unroll
    for (int k = 1; k < 20; ++k) {
      float v = row[5 + c0 + k];
      if (v > best) { best = v; bid = c0 + k; }   // strict >: first max within part
    }
    pbest[p][r] = best;
    pbid[p][r] = bid;
  }
  __syncthreads();

  if (tid < 64 && tid < nr) {
    const float* row = &lds[tid * ROW];
    float obj = row[4];
    float best = pbest[0][tid];
    int bid = pbid[0][tid];
#pragma unroll
    for (int q = 1; q < 4; ++q) {
      float v = pbest[q][tid];
      if (v > best) { best = v; bid = pbid[q][tid]; }  // ascending parts, strict >
    }
    float score = obj * best;
    bool valid = (obj > CONF) && (score > CONF);
    float sout = valid ? score : 0.0f;
    int n = r0 + tid;
    scores[(size_t)b * NN + n] = sout;
    cls[(size_t)b * NN + n] = (unsigned char)bid;
    if (valid) {
      unsigned int u = __float_as_uint(sout);   // in (0x3E800000, 0x3F800000]
      unsigned int bin = (u - 0x3E800001u) >> 12;
      if (bin > NBIN - 1) bin = NBIN - 1;
      atomicAdd(&hist[(size_t)b * NBIN + bin], 1u);
    }
  }
}

// ---------------- Stage 2a: pivot bin per batch (parallel suffix-scan) ----------------
__global__ __launch_bounds__(256) void pivot_kernel(const unsigned int* __restrict__ hist,
                                                    int* __restrict__ pivP) {
  int b = blockIdx.x;
  int t = threadIdx.x;
  const unsigned int* h = hist + (size_t)b * NBIN;
  __shared__ int sfx[256];
  int s = 0;
  for (int k = 0; k < 16; ++k) s += (int)h[t * 16 + k];
  sfx[t] = s;
  __syncthreads();
  for (int off = 1; off < 256; off <<= 1) {
    int v = (t + off < 256) ? sfx[t + off] : 0;
    __syncthreads();
    sfx[t] += v;
    __syncthreads();
  }
  int above = (t == 255) ? 0 : sfx[t + 1];
  if (sfx[t] >= TK && above < TK) {         // exactly one t (if total >= TK)
    int cum = above;
    for (int bin = t * 16 + 15; bin >= t * 16; --bin) {
      cum += (int)h[bin];
      if (cum >= TK) { pivP[b] = bin; break; }
    }
  }
  if (t == 0 && sfx[0] < TK) pivP[b] = 0;   // never with this data; safety
}

// ---------------- Stage 2b: grid-wide gather of candidates (bin >= P) ----------------
__global__ __launch_bounds__(256) void gather_kernel(const float* __restrict__ scores,
                                                     const int* __restrict__ pivP,
                                                     unsigned long long* __restrict__ ckey,
                                                     int* __restrict__ cnt) {
  int n = blockIdx.x * blockDim.x + threadIdx.x;
  int b = blockIdx.y;
  if (n >= NN) return;
  unsigned int u = __float_as_uint(scores[(size_t)b * NN + n]);
  if (u > 0x3E800000u) {
    unsigned int bin = (u - 0x3E800001u) >> 12;
    if (bin > NBIN - 1) bin = NBIN - 1;
    if (bin >= (unsigned int)pivP[b]) {
      int slot = atomicAdd(&cnt[b], 1);
      if (slot < CAND)
        ckey[(size_t)b * CAND + slot] = ((unsigned long long)u << 32) | (unsigned int)(~n);
    }
  }
}

// ---------------- Stage 2c: rank-place (1 block per 256 slots) + epilogue ----------------
__global__ __launch_bounds__(256) void rank_kernel(const float* __restrict__ pred,
                                                   const unsigned char* __restrict__ cls,
                                                   const unsigned long long* __restrict__ ckey,
                                                   const int* __restrict__ cnt,
                                                   float* __restrict__ tops,
                                                   float* __restrict__ boxes,
                                                   int* __restrict__ clsk) {
  int b = blockIdx.y;
  int t = threadIdx.x;
  int slot = blockIdx.x * 256 + t;
  int C = cnt[b]; if (C > CAND) C = CAND;
  __shared__ unsigned long long lk[CAND];  // 32 KB; only first C used
  const unsigned long long* gk = ckey + (size_t)b * CAND;
  for (int i = t; i < C; i += 256) lk[i] = gk[i];
  __syncthreads();

  if (slot < C) {
    unsigned long long mk = lk[slot];
    int r = 0;
    int j = 0;
    unsigned long long pf[8];
    for (; j + 8 <= C; j += 8) {
#pragma unroll
      for (int k = 0; k < 8; ++k) pf[k] = lk[j + k];   // broadcast, conflict-free
#pragma unroll
      for (int k = 0; k < 8; ++k) r += (pf[k] > mk) ? 1 : 0;
    }
    for (; j < C; ++j) r += (lk[j] > mk) ? 1 : 0;

    if (r < TK) {  // rank IS the final top_k position (unique keys)
      unsigned int ub = (unsigned int)(mk >> 32);
      int idx = (int)(~(unsigned int)mk);
      tops[(size_t)b * TK + r] = __uint_as_float(ub);
      clsk[(size_t)b * TK + r] = (int)cls[(size_t)b * NN + idx];
      const float* rowp = pred + ((size_t)b * NN + idx) * ROW;
      float cx = rowp[0], cy = rowp[1], w = rowp[2], h = rowp[3];
      float hw = w * 0.5f, hh = h * 0.5f;
      float* ob = boxes + ((size_t)b * TK + r) * 4;
      ob[0] = cx - hw; ob[1] = cy - hh; ob[2] = cx + hw; ob[3] = cy + hh;
    }
  } else if (slot < TK) {
    tops[(size_t)b * TK + slot] = 0.0f;
    clsk[(size_t)b * TK + slot] = 0;
    float* ob = boxes + ((size_t)b * TK + slot) * 4;
    ob[0] = 0.f; ob[1] = 0.f; ob[2] = 0.f; ob[3] = 0.f;
  }
}

// ---------------- Stage 3: greedy NMS, one wave per (batch, class) ----------------
__global__ __launch_bounds__(64) void nms_kernel(const float* __restrict__ tops,
                                                 const float* __restrict__ boxes,
                                                 const int* __restrict__ clsk,
                                                 int* __restrict__ keep) {
  int c = blockIdx.x;
  int b = blockIdx.y;
  int lane = threadIdx.x;
  __shared__ float sx1[TK], sy1[TK], sx2[TK], sy2[TK];
  __shared__ unsigned short spos[TK];
  __shared__ unsigned char skp[TK];

  int myc[32];
  float mytop[32];
#pragma unroll
  for (int it = 0; it < 32; ++it) {
    int j = it * 64 + lane;
    myc[it] = clsk[(size_t)b * TK + j];
    mytop[it] = tops[(size_t)b * TK + j];
  }

  float shift = (float)c * MAXWH;
  int m = 0;
#pragma unroll 4
  for (int it = 0; it < 32; ++it) {
    int j = it * 64 + lane;
    bool match = (myc[it] == c);
    unsigned long long bal = __ballot(match);
    int mp = m + __popcll(bal & ((1ull << lane) - 1ull));
    if (match) {
      spos[mp] = (unsigned short)j;
      const float* bx = boxes + ((size_t)b * TK + j) * 4;
      sx1[mp] = bx[0] + shift;
      sy1[mp] = bx[1] + shift;
      sx2[mp] = bx[2] + shift;
      sy2[mp] = bx[3] + shift;
      skp[mp] = (mytop[it] > 0.0f) ? 1 : 0;
    }
    m += (int)__popcll(bal);
  }
  __syncthreads();

  for (int i = 0; i < m; ++i) {
    __syncthreads();
    if (!skp[i]) continue;  // uniform across the wave
    float ax1 = sx1[i], ay1 = sy1[i], ax2 = sx2[i], ay2 = sy2[i];
    float aarea = (ax2 - ax1) * (ay2 - ay1);
    for (int j = i + 1 + lane; j < m; j += 64) {
      float bx1 = sx1[j], by1 = sy1[j], bx2 = sx2[j], by2 = sy2[j];
      float ltx = fmaxf(ax1, bx1), lty = fmaxf(ay1, by1);
      float rbx = fminf(ax2, bx2), rby = fminf(ay2, by2);
      float iw = fmaxf(rbx - ltx, 0.0f);
      float ih = fmaxf(rby - lty, 0.0f);
      float inter = iw * ih;
      float barea = (bx2 - bx1) * (by2 - by1);
      float iou = inter / (aarea + barea - inter + 1e-7f);
      if (iou > IOUT) skp[j] = 0;
    }
  }
  __syncthreads();

  for (int i = lane; i < m; i += 64) {
    keep[(size_t)b * TK + spos[i]] = skp[i];
  }
}

// ---------------- Stage 4: compact first 1000 kept + padding ----------------
__global__ __launch_bounds__(256) void out_kernel(const float* __restrict__ tops,
                                                  const float* __restrict__ boxes,
                                                  const int* __restrict__ clsk,
                                                  const int* __restrict__ keep,
                                                  float* __restrict__ out) {
  int b = blockIdx.x;
  int t = threadIdx.x;
  __shared__ int scnt[256];
  const int CH = TK / 256;  // 8
  int base = t * CH;
  int kp[CH];
  int cnt = 0;
  for (int k = 0; k < CH; ++k) {
    kp[k] = keep[(size_t)b * TK + base + k];
    cnt += kp[k];
  }
  scnt[t] = cnt;
  __syncthreads();
  for (int off = 1; off < 256; off <<= 1) {
    int v = (t >= off) ? scnt[t - off] : 0;
    __syncthreads();
    scnt[t] += v;
    __syncthreads();
  }
  int r = scnt[t] - cnt;
  int K = scnt[255];
  for (int k = 0; k < CH; ++k) {
    if (kp[k]) {
      if (r < MAXDET) {
        int j = base + k;
        float* o = out + ((size_t)b * MAXDET + r) * 6;
        const float* bx = boxes + ((size_t)b * TK + j) * 4;
        o[0] = bx[0]; o[1] = bx[1]; o[2] = bx[2]; o[3] = bx[3];
        o[4] = tops[(size_t)b * TK + j];
        o[5] = (float)clsk[(size_t)b * TK + j];
      }
      ++r;
    }
  }
  int Kc = K < MAXDET ? K : MAXDET;
  for (int r2 = Kc + t; r2 < MAXDET; r2 += 256) {
    float* o = out + ((size_t)b * MAXDET + r2) * 6;
    o[0] = 0.0f; o[1] = 0.0f; o[2] = 0.0f; o[3] = 0.0f; o[4] = 0.0f; o[5] = -1.0f;
  }
}

extern "C" void kernel_launch(void* const* d_in, const int* in_sizes, int n_in,
                              void* d_out, int out_size, void* d_ws, size_t ws_size,
                              hipStream_t stream) {
  const float* pred = (const float*)d_in[0];
  float* out = (float*)d_out;

  char* ws = (char*)d_ws;
  size_t off = 0;
  float* scores = (float*)(ws + off);         off += (size_t)BB * NN * 4;     // 1.6 MB
  unsigned char* cls = (unsigned char*)(ws + off); off += (size_t)BB * NN;    // 0.4 MB
  off = (off + 255) & ~(size_t)255;
  float* tops   = (float*)(ws + off);         off += (size_t)BB * TK * 4;
  float* boxes  = (float*)(ws + off);         off += (size_t)BB * TK * 16;
  int*   clsk   = (int*)(ws + off);           off += (size_t)BB * TK * 4;
  int*   keep   = (int*)(ws + off);           off += (size_t)BB * TK * 4;
  unsigned long long* ckey = (unsigned long long*)(ws + off); off += (size_t)BB * CAND * 8; // 0.5 MB
  unsigned int* hist = (unsigned int*)(ws + off); off += (size_t)BB * NBIN * 4;             // 256 KB
  int*   cnt    = (int*)(ws + off);           off += (size_t)BB * 4;
  int*   pivP   = (int*)(ws + off);           off += (size_t)BB * 4;
  (void)ws_size; (void)in_sizes; (void)n_in; (void)out_size;

  hipMemsetAsync(hist, 0, (size_t)BB * NBIN * 4 + (size_t)BB * 4, stream);
  score_kernel<<<dim3((NN + 63) / 64, BB), 256, 0, stream>>>(pred, scores, cls, hist);
  pivot_kernel<<<BB, 256, 0, stream>>>(hist, pivP);
  gather_kernel<<<dim3((NN + 255) / 256, BB), 256, 0, stream>>>(scores, pivP, ckey, cnt);
  rank_kernel<<<dim3(CAND / 256, BB), 256, 0, stream>>>(pred, cls, ckey, cnt, tops, boxes, clsk);
  nms_kernel<<<dim3(NCLS, BB), 64, 0, stream>>>(tops, boxes, clsk, keep);
  out_kernel<<<BB, 256, 0, stream>>>(tops, boxes, clsk, keep, out);
}